// Round 8
// baseline (177.913 us; speedup 1.0000x reference)
//
#include <hip/hip_runtime.h>

// B = IN = OUT = 512; T from out_size.
// v_t = P_t @ x^T [OUT,B]; G = x@x^T [B,B]
//   u = k*(M*e^{-t} + a*v);  h = (u>0);  s = (u>0.2)
//   v' = d*v + e*(h@G + bt*colsum(G))
// Round-8: NO quad table. Thread owns one column; h published by ballot; acc
// maintained by +-G[row][c] for flipped rows (delta) or rebuilt from set h bits,
// whichever touches fewer rows. G is 1 MB -> fully L2-resident (tab was 4 MB and
// thrashed the per-XCD L2: 18 MB HBM refetch). Prologue: ONE stacked GEMM over
// A=[W;P0;x] (grid 768 = 3 blocks/CU), bias+relu fused into the M rows.

#define NN 512
#define KC 64

// ---- Stacked NT GEMM: grid 768 = 48 row-tiles x 16 col-tiles.
// rt<16: M = relu(W·x^T + b); rt<32: V0 = P0·x^T; rt>=32: G = x·x^T.
// 32x32 tiles, 256 thr, 2x2 micro, KC=64.
__global__ __launch_bounds__(256) void gemm_stack_kernel(
    const float* __restrict__ x, const float* __restrict__ W,
    const float* __restrict__ P0, const float* __restrict__ bias,
    float* __restrict__ M, float* __restrict__ V0, float* __restrict__ G)
{
    const int tid = threadIdx.x;
    const int bid = blockIdx.x;          // 0..767
    const int rt = bid >> 4;             // 0..47
    const int ct = bid & 15;
    const int rb = (rt & 15) << 5;       // row offset within the source/dest
    const int cb = ct << 5;

    const float* A = (rt < 16) ? (W  + (size_t)rb * NN)
                   : (rt < 32) ? (P0 + (size_t)rb * NN)
                               : (x  + (size_t)rb * NN);
    float* D = (rt < 16) ? M : (rt < 32) ? V0 : G;
    const bool doRelu = (rt < 16);

    const int tx = tid & 15;             // cols 2tx, 2tx+1
    const int ty = tid >> 4;             // rows 2ty, 2ty+1

    __shared__ float At[KC][36];
    __shared__ float Bt[KC][36];

    float acc[2][2] = {{0.f, 0.f}, {0.f, 0.f}};

    const int lrow = tid >> 3;           // 0..31
    const int lk = (tid & 7) << 3;       // 0,8,...,56

    for (int k0 = 0; k0 < NN; k0 += KC) {
        const float4 aa = *(const float4*)(A + (size_t)lrow * NN + k0 + lk);
        const float4 ab = *(const float4*)(A + (size_t)lrow * NN + k0 + lk + 4);
        const float4 ba = *(const float4*)(x + (size_t)(cb + lrow) * NN + k0 + lk);
        const float4 bb = *(const float4*)(x + (size_t)(cb + lrow) * NN + k0 + lk + 4);
        __syncthreads();
        At[lk + 0][lrow] = aa.x; At[lk + 1][lrow] = aa.y;
        At[lk + 2][lrow] = aa.z; At[lk + 3][lrow] = aa.w;
        At[lk + 4][lrow] = ab.x; At[lk + 5][lrow] = ab.y;
        At[lk + 6][lrow] = ab.z; At[lk + 7][lrow] = ab.w;
        Bt[lk + 0][lrow] = ba.x; Bt[lk + 1][lrow] = ba.y;
        Bt[lk + 2][lrow] = ba.z; Bt[lk + 3][lrow] = ba.w;
        Bt[lk + 4][lrow] = bb.x; Bt[lk + 5][lrow] = bb.y;
        Bt[lk + 6][lrow] = bb.z; Bt[lk + 7][lrow] = bb.w;
        __syncthreads();

#pragma unroll
        for (int k = 0; k < KC; ++k) {
            const float2 av = *(const float2*)&At[k][2 * ty];
            const float2 bw = *(const float2*)&Bt[k][2 * tx];
            acc[0][0] = fmaf(av.x, bw.x, acc[0][0]);
            acc[0][1] = fmaf(av.x, bw.y, acc[0][1]);
            acc[1][0] = fmaf(av.y, bw.x, acc[1][0]);
            acc[1][1] = fmaf(av.y, bw.y, acc[1][1]);
        }
    }

#pragma unroll
    for (int i = 0; i < 2; ++i) {
        const int r = rb + 2 * ty + i;
        float2 o = make_float2(acc[i][0], acc[i][1]);
        if (doRelu) {
            const float bb2 = bias[r];
            o.x = fmaxf(o.x + bb2, 0.f);
            o.y = fmaxf(o.y + bb2, 0.f);
        }
        *(float2*)(D + (size_t)r * NN + cb + 2 * tx) = o;
    }
}

// ---- colsum: 8 blocks x 256 thr
__global__ __launch_bounds__(256) void colsum_kernel(
    const float* __restrict__ G, float* __restrict__ gs)
{
    __shared__ float red[4][64];
    const int tid = threadIdx.x;
    const int c = (blockIdx.x << 6) + (tid & 63);
    const int g = tid >> 6;
    float s = 0.f;
    for (int bp = 128 * g; bp < 128 * g + 128; ++bp) s += G[(size_t)bp * NN + c];
    if (g > 0) red[g][tid & 63] = s;
    __syncthreads();
    if (g == 0) gs[c] = ((s + red[1][tid & 63]) + red[2][tid & 63]) + red[3][tid & 63];
}

// ---- Main recurrence: 512 blocks x 512 threads. Thread owns col c = tid.
// Wave w publishes 64 h-bits via ballot into LDS; ONE barrier per step.
// Frozen steps read one 8B flag and skip. Transient: +-G[row][c] per flipped
// row, or rebuild from set h bits if that's fewer rows. G L2-resident (1 MB).
__global__ __launch_bounds__(512) void snn_bits2_kernel(
    const float* __restrict__ M, const float* __restrict__ G,
    const float* __restrict__ V0, const float* __restrict__ gs,
    const float* __restrict__ alpha, const float* __restrict__ eta,
    const float* __restrict__ beta, unsigned* __restrict__ sp, int T)
{
    const int tid = threadIdx.x;
    const int w = tid >> 6;
    const int lane = tid & 63;
    const int r = blockIdx.x;

    __shared__ unsigned long long lmask[2][8];
    __shared__ unsigned long long lflag[2];

    const float a = alpha[0], e = eta[0], bt = beta[0];
    const float kk = 0.2f;
    const float dd = 0.36787944117144233f;   // exp(-1)
    const float Vth = 0.2f;

    const size_t rc = (size_t)r * NN + tid;
    const float m = M[rc];
    float v = V0[rc];
    const float cg = e * bt * gs[tid];
    const float* Gc = G + tid;

    float acc = 0.f;
    unsigned long long o0 = 0, o1 = 0, o2 = 0, o3 = 0, o4 = 0, o5 = 0, o6 = 0, o7 = 0;
    unsigned long long myold = 0;     // own wave's old word (acc==0 <-> h==0: exact)
    float em = 1.0f;

    for (int t = 0; t < T; ++t) {
        const float u = kk * fmaf(a, v, m * em);
        const unsigned long long hb = __ballot(u > 0.f);
        const unsigned long long sb = __ballot(u > Vth);
        const int p = t & 1;
        if (lane == 0) {
            lmask[p][w] = hb;
            ((unsigned char*)&lflag[p])[w] = (hb != myold) ? (unsigned char)1 : (unsigned char)0;
            // sp words 2w,2w+1 of row: bit l <-> col 64w+l (matches expand layout)
            *(unsigned long long*)(sp + ((size_t)t * NN + r) * 16 + 2 * w) = sb;
        }
        __syncthreads();   // single barrier per step (masks double-buffered)

        if (lflag[p] != 0ull) {
            const unsigned long long n0 = lmask[p][0], n1 = lmask[p][1],
                n2 = lmask[p][2], n3 = lmask[p][3], n4 = lmask[p][4],
                n5 = lmask[p][5], n6 = lmask[p][6], n7 = lmask[p][7];
            const unsigned long long x0 = n0 ^ o0, x1 = n1 ^ o1, x2 = n2 ^ o2,
                x3 = n3 ^ o3, x4 = n4 ^ o4, x5 = n5 ^ o5, x6 = n6 ^ o6, x7 = n7 ^ o7;
            const int nx = __popcll(x0) + __popcll(x1) + __popcll(x2) + __popcll(x3)
                         + __popcll(x4) + __popcll(x5) + __popcll(x6) + __popcll(x7);
            const int nh = __popcll(n0) + __popcll(n1) + __popcll(n2) + __popcll(n3)
                         + __popcll(n4) + __popcll(n5) + __popcll(n6) + __popcll(n7);

            if (nx <= nh) {
                // signed deltas over flipped rows
#define DELTW(i, nw, xw) { unsigned long long d = (xw); \
                while (d) { const int b = __builtin_ctzll(d); d &= d - 1ull; \
                    const float gv = Gc[((size_t)(64 * i + b)) << 9]; \
                    acc += ((nw >> b) & 1ull) ? gv : -gv; } }
                DELTW(0, n0, x0) DELTW(1, n1, x1) DELTW(2, n2, x2) DELTW(3, n3, x3)
                DELTW(4, n4, x4) DELTW(5, n5, x5) DELTW(6, n6, x6) DELTW(7, n7, x7)
            } else {
                // rebuild from set h bits (fewer rows than flips)
                acc = 0.f;
#define FULLW(i, nw) { unsigned long long d = (nw); \
                while (d) { const int b = __builtin_ctzll(d); d &= d - 1ull; \
                    acc += Gc[((size_t)(64 * i + b)) << 9]; } }
                FULLW(0, n0) FULLW(1, n1) FULLW(2, n2) FULLW(3, n3)
                FULLW(4, n4) FULLW(5, n5) FULLW(6, n6) FULLW(7, n7)
            }
            o0 = n0; o1 = n1; o2 = n2; o3 = n3; o4 = n4; o5 = n5; o6 = n6; o7 = n7;
            myold = hb;
        }

        v = fmaf(dd, v, fmaf(e, acc, cg));
        em *= dd;
    }
}

// ---- Expand: out[t][b][o] = bit b of sp[t][o]. Coalesced float4 stores.
__global__ __launch_bounds__(256) void expand_kernel(
    const unsigned* __restrict__ sp, float* __restrict__ out)
{
    const int tid = threadIdx.x;
    const int t = blockIdx.x >> 3;
    const int bt8 = blockIdx.x & 7;

    __shared__ uint2 sh[NN];
    const uint2* spw = (const uint2*)sp;
    sh[tid]       = spw[((size_t)t * NN + tid) * 8 + bt8];
    sh[tid + 256] = spw[((size_t)t * NN + tid + 256) * 8 + bt8];
    __syncthreads();

    const int b = bt8 * 64 + (tid >> 2);
    const int sub = tid & 3;
    const int rw = (tid >> 2) >> 5;
    const int bit = b & 31;
    float* op = out + (size_t)t * (NN * NN) + (size_t)b * NN;

#pragma unroll 4
    for (int i = 0; i < 32; ++i) {
        const int o = sub * 4 + i * 16;
        const uint2 w0 = sh[o];
        const uint2 w1 = sh[o + 1];
        const uint2 w2 = sh[o + 2];
        const uint2 w3 = sh[o + 3];
        float4 f;
        f.x = (float)(((rw ? w0.y : w0.x) >> bit) & 1u);
        f.y = (float)(((rw ? w1.y : w1.x) >> bit) & 1u);
        f.z = (float)(((rw ? w2.y : w2.x) >> bit) & 1u);
        f.w = (float)(((rw ? w3.y : w3.x) >> bit) & 1u);
        *(float4*)(op + o) = f;
    }
}

// ---- Fallback (tiny ws): round-1 step kernel with direct strided writes.
__global__ __launch_bounds__(256) void snn_step_kernel(
    const float* __restrict__ M, const float* __restrict__ G,
    const float* __restrict__ V0, const float* __restrict__ gs,
    const float* __restrict__ alpha, const float* __restrict__ eta,
    const float* __restrict__ beta, float* __restrict__ out, int T)
{
    const int j = threadIdx.x;
    const int r0 = blockIdx.x * 2;
    const int c0 = 2 * j;
    const float a = alpha[0], e = eta[0], bt = beta[0];
    const float kk = 0.2f, dd = 0.36787944117144233f, Vth = 0.2f;

    float v00 = V0[r0 * NN + c0];
    float v01 = V0[r0 * NN + c0 + 1];
    float v10 = V0[(r0 + 1) * NN + c0];
    float v11 = V0[(r0 + 1) * NN + c0 + 1];
    const float m00 = M[r0 * NN + c0];
    const float m01 = M[r0 * NN + c0 + 1];
    const float m10 = M[(r0 + 1) * NN + c0];
    const float m11 = M[(r0 + 1) * NN + c0 + 1];
    const float gs0 = gs[c0];
    const float gs1 = gs[c0 + 1];

    __shared__ float2 hp[NN];
    float em = 1.0f;
    const float2* Gcol = (const float2*)G + j;

    for (int t = 0; t < T; ++t) {
        const float u00 = kk * (m00 * em + a * v00);
        const float u01 = kk * (m01 * em + a * v01);
        const float u10 = kk * (m10 * em + a * v10);
        const float u11 = kk * (m11 * em + a * v11);

        float* outp = out + (size_t)t * (NN * NN);
        float2 sA = make_float2(u00 > Vth ? 1.f : 0.f, u10 > Vth ? 1.f : 0.f);
        float2 sB = make_float2(u01 > Vth ? 1.f : 0.f, u11 > Vth ? 1.f : 0.f);
        *(float2*)(outp + (size_t)c0 * NN + r0) = sA;
        *(float2*)(outp + (size_t)(c0 + 1) * NN + r0) = sB;

        hp[c0]     = make_float2(u00 > 0.f ? 1.f : 0.f, u10 > 0.f ? 1.f : 0.f);
        hp[c0 + 1] = make_float2(u01 > 0.f ? 1.f : 0.f, u11 > 0.f ? 1.f : 0.f);
        __syncthreads();

        float acc00 = 0.f, acc01 = 0.f, acc10 = 0.f, acc11 = 0.f;
#pragma unroll 8
        for (int bp = 0; bp < NN; ++bp) {
            float2 h = hp[bp];
            float2 g = Gcol[(size_t)bp * 256];
            acc00 = fmaf(h.x, g.x, acc00);
            acc01 = fmaf(h.x, g.y, acc01);
            acc10 = fmaf(h.y, g.x, acc10);
            acc11 = fmaf(h.y, g.y, acc11);
        }

        v00 = dd * v00 + e * (acc00 + bt * gs0);
        v01 = dd * v01 + e * (acc01 + bt * gs1);
        v10 = dd * v10 + e * (acc10 + bt * gs0);
        v11 = dd * v11 + e * (acc11 + bt * gs1);
        em *= dd;
        __syncthreads();
    }
}

extern "C" void kernel_launch(void* const* d_in, const int* in_sizes, int n_in,
                              void* d_out, int out_size, void* d_ws, size_t ws_size,
                              hipStream_t stream)
{
    const float* x     = (const float*)d_in[0];
    const float* W     = (const float*)d_in[1];
    const float* bias  = (const float*)d_in[2];
    const float* alpha = (const float*)d_in[3];
    const float* eta   = (const float*)d_in[4];
    const float* beta  = (const float*)d_in[5];
    const float* P0    = (const float*)d_in[6];
    (void)in_sizes; (void)n_in;

    const int T = out_size / (NN * NN);

    float* ws  = (float*)d_ws;
    float* M   = ws;                           // [512,512] final (relu+bias)
    float* V0  = ws + NN * NN;                 // [512,512]
    float* G   = ws + 2 * NN * NN;             // [512,512] = 1 MB
    float* gsv = ws + 3 * NN * NN;             // [512]
    unsigned* sp = (unsigned*)(gsv + NN);      // [T][512][16] words

    const size_t need_main = ((size_t)3 * NN * NN + NN) * 4 + (size_t)T * NN * 16 * 4;

    hipLaunchKernelGGL(gemm_stack_kernel, dim3(768), dim3(256), 0, stream,
                       x, W, P0, bias, M, V0, G);
    hipLaunchKernelGGL(colsum_kernel, dim3(8), dim3(256), 0, stream, G, gsv);

    if (ws_size >= need_main) {
        hipLaunchKernelGGL(snn_bits2_kernel, dim3(NN), dim3(512), 0, stream,
                           M, G, V0, gsv, alpha, eta, beta, sp, T);
        hipLaunchKernelGGL(expand_kernel, dim3(T * 8), dim3(256), 0, stream,
                           sp, (float*)d_out);
    } else {
        hipLaunchKernelGGL(snn_step_kernel, dim3(256), dim3(256), 0, stream,
                           M, G, V0, gsv, alpha, eta, beta, (float*)d_out, T);
    }
}